// Round 6
// baseline (12.134 us; speedup 1.0000x reference)
//
#include <hip/hip_runtime.h>
#include <math.h>

// Analytic simulation:
//  - per-qubit product states tracked as real Bloch vectors (SO(3) rotations),
//  - layer-2 observables O_q = U^dag Z U = n·sigma with n = Rx(-a)Ry(-b) z_hat,
//  - CNOT-ring pullback of each Pauli string precomputed at COMPILE TIME
//    (symplectic conjugation is data-independent) into a 7 KB .rodata table,
//  - expectation of a Pauli string on a product state = product of Bloch components.
// R6: (a) norm via Gram matrix: ||y||^2 = q^T G q + 2 h^T q + b^T b, with
//     G=W^T W, h=W^T b, b^T b (15 scalars) computed by the otherwise-idle
//     waves 2..7 BEFORE barrier 1 -> barrier 3 + second butterfly removed;
// (b) DPP wave-sum (v_mov_dpp+v_add, lane 63 holds total) replaces the
//     ds_bpermute shuffle butterfly in phase C.

struct STab {
  unsigned lo[7][128];  // xm(20b) | sgn<<20 | digits<<21 (2b per wire)
  unsigned hi[7][128];  // zm(20b)
};

constexpr STab make_tab() {
  STab T{};
  const int g_nw[7] = {4, 4, 4, 4, 3, 2, 3};
  const int g_w0[7] = {0, 0, 0, 0, 1, 0, 0};
  for (int g = 0; g < 7; ++g) {
    const int nw = g_nw[g], w0 = g_w0[g];
    int nstr = 1;
    for (int k = 0; k < nw; ++k) nstr *= 3;
    for (int t = 0; t < nstr; ++t) {
      unsigned xm = 0, zm = 0, dg = 0;
      int tt = t;
      for (int k = 0; k < nw; ++k) {
        const int d = tt % 3;  // 0=X,1=Y,2=Z
        tt /= 3;
        dg |= (unsigned)d << (2 * k);
        const int w = w0 + k;
        if (d != 2) xm |= 1u << w;
        if (d != 0) zm |= 1u << w;
      }
      // Pull back through CNOT ring: conjugate by C(19,0) first ... C(0,1) last.
      unsigned sgn = 0;
      for (int c = 19; c >= 0; --c) {
        const int tq = (c + 1) % 20;
        const unsigned xc = (xm >> c) & 1u, zc = (zm >> c) & 1u;
        const unsigned xt = (xm >> tq) & 1u, zt = (zm >> tq) & 1u;
        sgn ^= xc & zt & (xt ^ zc ^ 1u);
        xm ^= xc << tq;  // x_t ^= x_c
        zm ^= zt << c;   // z_c ^= z_t
      }
      T.lo[g][t] = xm | (sgn << 20) | (dg << 21);
      T.hi[g][t] = zm;
    }
  }
  return T;
}

__device__ constexpr STab TAB = make_tab();

// Hardware sin/cos: v_sin_f32/v_cos_f32 take revolutions. Inputs here are
// |t| <~ 6 rad (<1 revolution) -- no range reduction needed, ~2 ulp.
__device__ __forceinline__ void fsc(float t, float& s, float& c) {
  const float r = t * 0.15915494309189535f;  // 1/(2*pi)
  s = __builtin_amdgcn_sinf(r);
  c = __builtin_amdgcn_cosf(r);
}

__device__ __forceinline__ void brx(float t, float& x, float& y, float& z) {
  float s, c; fsc(t, s, c);
  float y2 = c * y - s * z;
  z = s * y + c * z;
  y = y2;
  (void)x;
}
__device__ __forceinline__ void bry(float t, float& x, float& y, float& z) {
  float s, c; fsc(t, s, c);
  float z2 = c * z - s * x;
  x = s * z + c * x;
  z = z2;
  (void)y;
}
__device__ __forceinline__ void brz(float t, float& x, float& y, float& z) {
  float s, c; fsc(t, s, c);
  float x2 = c * x - s * y;
  y = s * x + c * y;
  x = x2;
  (void)z;
}

// DPP wave sum: classic GCN sequence; total lands in lane 63.
template <int CTRL>
__device__ __forceinline__ float dpp_add(float x) {
  const int y = __builtin_amdgcn_update_dpp(0, __float_as_int(x), CTRL, 0xF, 0xF, true);
  return x + __int_as_float(y);
}
__device__ __forceinline__ float wave_sum63(float x) {
  x = dpp_add<0x111>(x);  // row_shr:1
  x = dpp_add<0x112>(x);  // row_shr:2
  x = dpp_add<0x114>(x);  // row_shr:4
  x = dpp_add<0x118>(x);  // row_shr:8  -> lane15 of each row = row sum
  x = dpp_add<0x142>(x);  // row_bcast15
  x = dpp_add<0x143>(x);  // row_bcast31 -> lane63 = total
  return x;
}

__global__ __launch_bounds__(512) void qie_kernel(
    const float* __restrict__ x,     // [8,16,4,3]
    const float* __restrict__ posw,  // [16,2]
    const float* __restrict__ l1w,   // [20,3]
    const float* __restrict__ l2w,   // [16,3]
    const float* __restrict__ hw,    // [512,4]
    const float* __restrict__ hb,    // [512]
    float* __restrict__ out)         // [8,512]
{
  const int img = blockIdx.x;
  const int tid = threadIdx.x;
  const int wid = tid >> 6, lane = tid & 63;

  // Entry prefetch: head weights + this lane's two Pauli-string table entries.
  const float hw0 = hw[tid * 4 + 0];
  const float hw1 = hw[tid * 4 + 1];
  const float hw2 = hw[tid * 4 + 2];
  const float hw3 = hw[tid * 4 + 3];
  const float hbb = hb[tid];
  unsigned lo1 = 0, hi1 = 0, lo2 = 0, hi2 = 0;
  if (wid < 7) {
    lo1 = TAB.lo[wid][lane];
    hi1 = TAB.hi[wid][lane];
    lo2 = TAB.lo[wid][lane + 64];
    hi2 = TAB.hi[wid][lane + 64];
  }

  __shared__ float bl[4][20][3];  // Bloch vectors: [block][qubit][x,y,z]
  __shared__ float nv[16][3];     // observable Bloch vectors
  __shared__ float eg[7];         // group expectations
  __shared__ float gm[15];        // Gram scalars: g00,g01,g02,g03,g11,g12,g13,g22,g23,g33,h0..h3,bb

  // ---- Pre-barrier-1 work, split by wave ----
  if (tid < 80) {
    // Phase A: per-qubit Bloch vectors (waves 0..1)
    const int b = tid / 20, i = tid % 20;
    const int p = 4 * b + i / 5, j = i % 5;
    float nx = 0.f, ny = 0.f, nz = 1.f;  // |0> = z_hat
    if (j < 4) {
      const float* a = x + ((img * 16 + p) * 4 + j) * 3;
      brx(a[0], nx, ny, nz);
      bry(a[1], nx, ny, nz);
      brz(a[2], nx, ny, nz);
    } else {
      brx(posw[p * 2 + 0], nx, ny, nz);
      bry(posw[p * 2 + 1], nx, ny, nz);
    }
    brx(l1w[i * 3 + 0], nx, ny, nz);
    bry(l1w[i * 3 + 1], nx, ny, nz);
    brz(l1w[i * 3 + 2], nx, ny, nz);
    bl[b][i][0] = nx; bl[b][i][1] = ny; bl[b][i][2] = nz;
  } else if (tid < 96) {
    // Phase B: O_q = n·sigma, n = Rx(-a)Ry(-b) z_hat (Rz drops out)
    const int q = tid - 80;
    float sa, ca, sb, cb;
    fsc(l2w[q * 3 + 0], sa, ca);
    fsc(l2w[q * 3 + 1], sb, cb);
    nv[q][0] = -sb;       // X coeff
    nv[q][1] = sa * cb;   // Y coeff
    nv[q][2] = ca * cb;   // Z coeff
  } else if (tid >= 128) {
    // Gram precompute on waves 2..7 (idle during phase A). Each wave reduces
    // the values v with v % 6 == wid-2; DPP sum -> lane 63 writes LDS.
    const int wv = wid - 2;  // 0..5
    const float4* __restrict__ hw4 = (const float4*)hw;
    float wx[8], wy[8], wz[8], ww[8], wb[8];
#pragma unroll
    for (int k = 0; k < 8; ++k) {
      const int r = lane + 64 * k;
      const float4 t = hw4[r];
      wx[k] = t.x; wy[k] = t.y; wz[k] = t.z; ww[k] = t.w;
      wb[k] = hb[r];
    }
    auto dot8 = [](const float (&A)[8], const float (&B)[8]) {
      float s = 0.f;
#pragma unroll
      for (int k = 0; k < 8; ++k) s += A[k] * B[k];
      return s;
    };
#define REDW(v, A, B)                                   \
  if ((v) % 6 == wv) {                                  \
    const float _r = wave_sum63(dot8(A, B));            \
    if (lane == 63) gm[v] = _r;                         \
  }
    REDW(0, wx, wx) REDW(1, wx, wy) REDW(2, wx, wz) REDW(3, wx, ww)
    REDW(4, wy, wy) REDW(5, wy, wz) REDW(6, wy, ww)
    REDW(7, wz, wz) REDW(8, wz, ww)
    REDW(9, ww, ww)
    REDW(10, wx, wb) REDW(11, wy, wb) REDW(12, wz, wb) REDW(13, ww, wb)
    REDW(14, wb, wb)
#undef REDW
  }
  __syncthreads();

  // ---- Phase C: 7 expectation groups, one wave each ----
  // g0..g3: Efull[b] wires {0..3}; g4: eA wires {1,2,3}; g5: e1 {0,1}; g6: e2 {0,1,2}.
  if (wid < 7) {
    const int g_nw[7] = {4, 4, 4, 4, 3, 2, 3};
    const int g_qb[7] = {0, 1, 2, 3, 0, 0, 0};
    const int g_w0[7] = {0, 0, 0, 0, 1, 0, 0};
    const int g_ns[7] = {81, 81, 81, 81, 27, 9, 27};
    const int nw = g_nw[wid], qb = g_qb[wid], w0 = g_w0[wid], nstr = g_ns[wid];

    auto eval = [&](unsigned lo, unsigned hi) -> float {
      float coeff = 1.0f;
      const unsigned dg = lo >> 21;
      for (int k = 0; k < nw; ++k)
        coeff *= nv[4 * qb + w0 + k][(dg >> (2 * k)) & 3u];
      float val = ((lo >> 20) & 1u) ? -coeff : coeff;
      const unsigned xm = lo & 0xFFFFFu, zm = hi;
      unsigned um = xm | zm;
      while (um) {
        const int i = __builtin_ctz(um);
        um &= um - 1;
        const unsigned xi = (xm >> i) & 1u, zi = (zm >> i) & 1u;
        val *= bl[qb][i][xi ? (zi ? 1 : 0) : 2];
      }
      return val;
    };

    float acc = 0.0f;
    if (lane < nstr) acc = eval(lo1, hi1);
    if (lane + 64 < nstr) acc += eval(lo2, hi2);
    acc = wave_sum63(acc);
    if (lane == 63) eg[wid] = acc;
  }
  __syncthreads();

  // ---- head + L2 normalize (norm^2 from Gram: no block reduction) ----
  const float q0 = eg[4] * eg[1] * eg[2] * eg[3];  // e0
  const float q1 = eg[5];                          // e1
  const float q2 = eg[6];                          // e2
  const float q3 = eg[0];                          // e3 = Efull[0]

  const float y = q0 * hw0 + q1 * hw1 + q2 * hw2 + q3 * hw3 + hbb;
  const float s =
      q0 * q0 * gm[0] + q1 * q1 * gm[4] + q2 * q2 * gm[7] + q3 * q3 * gm[9] +
      2.f * (q0 * (q1 * gm[1] + q2 * gm[2] + q3 * gm[3]) +
             q1 * (q2 * gm[5] + q3 * gm[6]) + q2 * q3 * gm[8] +
             q0 * gm[10] + q1 * gm[11] + q2 * gm[12] + q3 * gm[13]) +
      gm[14];
  const float rn = __builtin_amdgcn_rsqf(fmaxf(s, 1e-24f));
  out[img * 512 + tid] = y * rn;
}

extern "C" void kernel_launch(void* const* d_in, const int* in_sizes, int n_in,
                              void* d_out, int out_size, void* d_ws, size_t ws_size,
                              hipStream_t stream) {
  const float* x    = (const float*)d_in[0];  // [8,16,4,3]
  const float* posw = (const float*)d_in[1];  // [16,2]
  const float* l1w  = (const float*)d_in[2];  // [20,3]
  const float* l2w  = (const float*)d_in[3];  // [16,3]
  const float* hw   = (const float*)d_in[4];  // [512,4]
  const float* hb   = (const float*)d_in[5];  // [512]
  float* out = (float*)d_out;                 // [8,512]
  qie_kernel<<<8, 512, 0, stream>>>(x, posw, l1w, l2w, hw, hb, out);
}

// Round 7
// 10.236 us; speedup vs baseline: 1.1854x; 1.1854x over previous
//
#include <hip/hip_runtime.h>
#include <math.h>

// Analytic simulation:
//  - per-qubit product states tracked as real Bloch vectors (SO(3) rotations),
//  - layer-2 observables O_q = U^dag Z U = n·sigma with n = Rx(-a)Ry(-b) z_hat,
//  - CNOT-ring pullback of each Pauli string precomputed at COMPILE TIME
//    (symplectic conjugation is data-independent) into a 7 KB .rodata table,
//  - expectation of a Pauli string on a product state = product of Bloch components.
// R7 = R5 winner + DPP wave reductions (v_mov_dpp+v_add, total in lane 63)
// replacing both ds_bpermute shuffle butterflies. R6's Gram-norm reverted:
// its redundant 10KB head loads on waves 2..7 slipped barrier 1 (-1.4 us).

struct STab {
  unsigned lo[7][128];  // xm(20b) | sgn<<20 | digits<<21 (2b per wire)
  unsigned hi[7][128];  // zm(20b)
};

constexpr STab make_tab() {
  STab T{};
  const int g_nw[7] = {4, 4, 4, 4, 3, 2, 3};
  const int g_w0[7] = {0, 0, 0, 0, 1, 0, 0};
  for (int g = 0; g < 7; ++g) {
    const int nw = g_nw[g], w0 = g_w0[g];
    int nstr = 1;
    for (int k = 0; k < nw; ++k) nstr *= 3;
    for (int t = 0; t < nstr; ++t) {
      unsigned xm = 0, zm = 0, dg = 0;
      int tt = t;
      for (int k = 0; k < nw; ++k) {
        const int d = tt % 3;  // 0=X,1=Y,2=Z
        tt /= 3;
        dg |= (unsigned)d << (2 * k);
        const int w = w0 + k;
        if (d != 2) xm |= 1u << w;
        if (d != 0) zm |= 1u << w;
      }
      // Pull back through CNOT ring: conjugate by C(19,0) first ... C(0,1) last.
      unsigned sgn = 0;
      for (int c = 19; c >= 0; --c) {
        const int tq = (c + 1) % 20;
        const unsigned xc = (xm >> c) & 1u, zc = (zm >> c) & 1u;
        const unsigned xt = (xm >> tq) & 1u, zt = (zm >> tq) & 1u;
        sgn ^= xc & zt & (xt ^ zc ^ 1u);
        xm ^= xc << tq;  // x_t ^= x_c
        zm ^= zt << c;   // z_c ^= z_t
      }
      T.lo[g][t] = xm | (sgn << 20) | (dg << 21);
      T.hi[g][t] = zm;
    }
  }
  return T;
}

__device__ constexpr STab TAB = make_tab();

// Hardware sin/cos: v_sin_f32/v_cos_f32 take revolutions. Inputs here are
// |t| <~ 6 rad (<1 revolution) -- no range reduction needed, ~2 ulp.
__device__ __forceinline__ void fsc(float t, float& s, float& c) {
  const float r = t * 0.15915494309189535f;  // 1/(2*pi)
  s = __builtin_amdgcn_sinf(r);
  c = __builtin_amdgcn_cosf(r);
}

__device__ __forceinline__ void brx(float t, float& x, float& y, float& z) {
  float s, c; fsc(t, s, c);
  float y2 = c * y - s * z;
  z = s * y + c * z;
  y = y2;
  (void)x;
}
__device__ __forceinline__ void bry(float t, float& x, float& y, float& z) {
  float s, c; fsc(t, s, c);
  float z2 = c * z - s * x;
  x = s * z + c * x;
  z = z2;
  (void)y;
}
__device__ __forceinline__ void brz(float t, float& x, float& y, float& z) {
  float s, c; fsc(t, s, c);
  float x2 = c * x - s * y;
  y = s * x + c * y;
  x = x2;
  (void)z;
}

// DPP wave sum: row_shr 1/2/4/8 then row_bcast15/31; total lands in lane 63.
// bound_ctrl=true -> out-of-range source lanes contribute 0.
template <int CTRL>
__device__ __forceinline__ float dpp_add(float x) {
  const int y = __builtin_amdgcn_update_dpp(0, __float_as_int(x), CTRL, 0xF, 0xF, true);
  return x + __int_as_float(y);
}
__device__ __forceinline__ float wave_sum63(float x) {
  x = dpp_add<0x111>(x);  // row_shr:1
  x = dpp_add<0x112>(x);  // row_shr:2
  x = dpp_add<0x114>(x);  // row_shr:4
  x = dpp_add<0x118>(x);  // row_shr:8  -> lane 15 of each row = row sum
  x = dpp_add<0x142>(x);  // row_bcast15
  x = dpp_add<0x143>(x);  // row_bcast31 -> lane 63 = total
  return x;
}

__global__ __launch_bounds__(512) void qie_kernel(
    const float* __restrict__ x,     // [8,16,4,3]
    const float* __restrict__ posw,  // [16,2]
    const float* __restrict__ l1w,   // [20,3]
    const float* __restrict__ l2w,   // [16,3]
    const float* __restrict__ hw,    // [512,4]
    const float* __restrict__ hb,    // [512]
    float* __restrict__ out)         // [8,512]
{
  const int img = blockIdx.x;
  const int tid = threadIdx.x;
  const int wid = tid >> 6, lane = tid & 63;

  // Entry prefetch: head weights + this lane's two Pauli-string table entries.
  const float hw0 = hw[tid * 4 + 0];
  const float hw1 = hw[tid * 4 + 1];
  const float hw2 = hw[tid * 4 + 2];
  const float hw3 = hw[tid * 4 + 3];
  const float hbb = hb[tid];
  unsigned lo1 = 0, hi1 = 0, lo2 = 0, hi2 = 0;
  if (wid < 7) {
    lo1 = TAB.lo[wid][lane];
    hi1 = TAB.hi[wid][lane];
    lo2 = TAB.lo[wid][lane + 64];
    hi2 = TAB.hi[wid][lane + 64];
  }

  __shared__ float bl[4][20][3];  // Bloch vectors: [block][qubit][x,y,z]
  __shared__ float nv[16][3];     // observable Bloch vectors
  __shared__ float eg[7];         // group expectations
  __shared__ float red[8];        // norm partials

  // ---- Phase A: per-qubit Bloch vectors (threads 0..79) ----
  if (tid < 80) {
    const int b = tid / 20, i = tid % 20;
    const int p = 4 * b + i / 5, j = i % 5;
    float nx = 0.f, ny = 0.f, nz = 1.f;  // |0> = z_hat
    if (j < 4) {
      const float* a = x + ((img * 16 + p) * 4 + j) * 3;
      brx(a[0], nx, ny, nz);
      bry(a[1], nx, ny, nz);
      brz(a[2], nx, ny, nz);
    } else {
      brx(posw[p * 2 + 0], nx, ny, nz);
      bry(posw[p * 2 + 1], nx, ny, nz);
    }
    brx(l1w[i * 3 + 0], nx, ny, nz);
    bry(l1w[i * 3 + 1], nx, ny, nz);
    brz(l1w[i * 3 + 2], nx, ny, nz);
    bl[b][i][0] = nx; bl[b][i][1] = ny; bl[b][i][2] = nz;
  } else if (tid < 96) {
    // ---- Phase B: O_q = n·sigma, n = Rx(-a)Ry(-b) z_hat (Rz drops out) ----
    const int q = tid - 80;
    float sa, ca, sb, cb;
    fsc(l2w[q * 3 + 0], sa, ca);
    fsc(l2w[q * 3 + 1], sb, cb);
    nv[q][0] = -sb;       // X coeff
    nv[q][1] = sa * cb;   // Y coeff
    nv[q][2] = ca * cb;   // Z coeff
  }
  __syncthreads();

  // ---- Phase C: 7 expectation groups, one wave each ----
  // g0..g3: Efull[b] wires {0..3}; g4: eA wires {1,2,3}; g5: e1 {0,1}; g6: e2 {0,1,2}.
  if (wid < 7) {
    const int g_nw[7] = {4, 4, 4, 4, 3, 2, 3};
    const int g_qb[7] = {0, 1, 2, 3, 0, 0, 0};
    const int g_w0[7] = {0, 0, 0, 0, 1, 0, 0};
    const int g_ns[7] = {81, 81, 81, 81, 27, 9, 27};
    const int nw = g_nw[wid], qb = g_qb[wid], w0 = g_w0[wid], nstr = g_ns[wid];

    auto eval = [&](unsigned lo, unsigned hi) -> float {
      float coeff = 1.0f;
      const unsigned dg = lo >> 21;
      for (int k = 0; k < nw; ++k)
        coeff *= nv[4 * qb + w0 + k][(dg >> (2 * k)) & 3u];
      float val = ((lo >> 20) & 1u) ? -coeff : coeff;
      const unsigned xm = lo & 0xFFFFFu, zm = hi;
      unsigned um = xm | zm;
      while (um) {
        const int i = __builtin_ctz(um);
        um &= um - 1;
        const unsigned xi = (xm >> i) & 1u, zi = (zm >> i) & 1u;
        val *= bl[qb][i][xi ? (zi ? 1 : 0) : 2];
      }
      return val;
    };

    float acc = 0.0f;
    if (lane < nstr) acc = eval(lo1, hi1);
    if (lane + 64 < nstr) acc += eval(lo2, hi2);
    acc = wave_sum63(acc);
    if (lane == 63) eg[wid] = acc;
  }
  __syncthreads();

  // ---- head + L2 normalize ----
  const float q0 = eg[4] * eg[1] * eg[2] * eg[3];  // e0
  const float q1 = eg[5];                          // e1
  const float q2 = eg[6];                          // e2
  const float q3 = eg[0];                          // e3 = Efull[0]

  const float y = q0 * hw0 + q1 * hw1 + q2 * hw2 + q3 * hw3 + hbb;
  float ss = wave_sum63(y * y);
  if (lane == 63) red[wid] = ss;
  __syncthreads();
  const float s = red[0] + red[1] + red[2] + red[3] + red[4] + red[5] + red[6] + red[7];
  const float rn = __builtin_amdgcn_rsqf(fmaxf(s, 1e-24f));
  out[img * 512 + tid] = y * rn;
}

extern "C" void kernel_launch(void* const* d_in, const int* in_sizes, int n_in,
                              void* d_out, int out_size, void* d_ws, size_t ws_size,
                              hipStream_t stream) {
  const float* x    = (const float*)d_in[0];  // [8,16,4,3]
  const float* posw = (const float*)d_in[1];  // [16,2]
  const float* l1w  = (const float*)d_in[2];  // [20,3]
  const float* l2w  = (const float*)d_in[3];  // [16,3]
  const float* hw   = (const float*)d_in[4];  // [512,4]
  const float* hb   = (const float*)d_in[5];  // [512]
  float* out = (float*)d_out;                 // [8,512]
  qie_kernel<<<8, 512, 0, stream>>>(x, posw, l1w, l2w, hw, hb, out);
}